// Round 12
// baseline (390.454 us; speedup 1.0000x reference)
//
#include <hip/hip_runtime.h>
#include <hip/hip_bf16.h>

#define NN 50000
#define EE 800000
#define DD 128
#define NTILES_MAX 100000         // sum max(1, ceil(cnt/16)) <= NN + EE/16 = 100000

typedef __attribute__((ext_vector_type(8))) short bf16x8;
typedef __attribute__((ext_vector_type(4))) float f32x4;

__device__ __forceinline__ short f2bf(float f) {
    __hip_bfloat16 h = __float2bfloat16(f);
    return __builtin_bit_cast(short, h);
}

__device__ __forceinline__ float bf2f(short s) {
    unsigned int u = ((unsigned int)(unsigned short)s) << 16;
    return __builtin_bit_cast(float, u);
}

// fast silu: v_rcp_f32 instead of the ~10-instr exact-div sequence.
__device__ __forceinline__ float fast_silu(float x) {
    return x * __builtin_amdgcn_rcpf(1.0f + __expf(-x));
}

// convert 8 consecutive floats to a bf16x8 A-fragment
__device__ __forceinline__ bf16x8 load_frag_f32(const float* p) {
    f32x4 a = *(const f32x4*)p;
    f32x4 b = *(const f32x4*)(p + 4);
    bf16x8 t;
    t[0] = f2bf(a[0]); t[1] = f2bf(a[1]); t[2] = f2bf(a[2]); t[3] = f2bf(a[3]);
    t[4] = f2bf(b[0]); t[5] = f2bf(b[1]); t[6] = f2bf(b[2]); t[7] = f2bf(b[3]);
    return t;
}

// ---- prep_all: blocks [0,3125): receiver histogram.
//      blocks [3125,3510): pack 6 weight blocks into MFMA B-frag order + w1c.
//      (h->bf16 conversion eliminated: consumers convert at use) ----
__global__ void prep_all_kernel(const int* __restrict__ ei, int* __restrict__ cnt,
                                const float* __restrict__ W1, const float* __restrict__ W2,
                                const float* __restrict__ U1, const float* __restrict__ U2,
                                unsigned short* __restrict__ packs,
                                float* __restrict__ w1c_out) {
    if (blockIdx.x < 3125) {
        int e = blockIdx.x * 256 + threadIdx.x;          // 800000 exactly
        atomicAdd(&cnt[ei[EE + e]], 1);                  // receiver histogram
        return;
    }
    int t = (blockIdx.x - 3125) * blockDim.x + threadIdx.x;
    if (t >= 98304) {
        if (t < 98432) { int d = t - 98304; w1c_out[d] = W1[d * 257 + 256]; }
        return;
    }
    int mat = t >> 14;
    int r = t & 16383;
    int j = r & 7;
    int lane = (r >> 3) & 63;
    int f = r >> 9;            // 0..31
    int ks = f & 3, nt = f >> 2;
    int n = nt * 16 + (lane & 15);
    int k = ks * 32 + (lane >> 4) * 8 + j;
    float v;
    switch (mat) {
        case 0: v = W1[n * 257 + k];        break;  // W1a (vs h_sender)
        case 1: v = W1[n * 257 + 128 + k];  break;  // W1b (vs h_receiver)
        case 2: v = W2[n * 128 + k];        break;  // W2
        case 3: v = U1[n * 256 + k];        break;  // U1a (vs h)
        case 4: v = U1[n * 256 + 128 + k];  break;  // U1b (vs agg)
        default: v = U2[n * 128 + k];       break;  // U2
    }
    packs[t] = (unsigned short)f2bf(v);
}

// ---- alloc: parallel atomic bucket allocation. Every receiver gets >=1 tile.
//      Single-tile buckets: sign-bit flag -> edge PLAIN-STORES the row.
//      Multi-tile buckets: zero the agg row here; edge tiles atomicAdd. ----
__global__ void alloc_kernel(const int* __restrict__ cnt, int* __restrict__ tileCtr,
                             int* __restrict__ cursor, int2* __restrict__ tinfo,
                             float4* __restrict__ agg4) {
    int i = blockIdx.x * 256 + threadIdx.x;              // 196 blocks: 50176 >= NN
    if (i >= NN) return;
    int c = cnt[i];
    int ntt = (c + 15) >> 4;
    if (ntt == 0) ntt = 1;                               // empty: 1 all-masked tile
    int tb = atomicAdd(tileCtr, ntt);
    int base = tb << 4;
    cursor[i] = base;
    int end = base + c;                                  // first invalid slot
    if (ntt == 1) {
        tinfo[tb] = make_int2(i | (int)0x80000000, end); // single-tile: store flag
    } else {
        for (int k = 0; k < ntt; k++) tinfo[tb + k] = make_int2(i, end);
        float4* row = agg4 + (size_t)i * 32;             // zero row for atomics
        #pragma unroll 8
        for (int k = 0; k < 32; k++) row[k] = make_float4(0.f, 0.f, 0.f, 0.f);
    }
}

// ---- prep_g (blocks [0,782)) + scatter (blocks [782,3907)) ----
__global__ __launch_bounds__(256, 2) void prep_g_scatter_kernel(
    const float* __restrict__ h,
    const bf16x8* __restrict__ w1a_pack,
    const bf16x8* __restrict__ w1b_pack,
    const float* __restrict__ b1,
    unsigned short* __restrict__ G,
    const int* __restrict__ ei,
    int* __restrict__ cursor,
    int* __restrict__ ssr)
{
    if (blockIdx.x >= 782) {
        // scatter sender ids into padded receiver buckets (4B random RMW)
        int e = (blockIdx.x - 782) * 256 + threadIdx.x;   // 3125*256 = 800000 exactly
        int s = ei[e], r = ei[EE + e];
        int pos = atomicAdd(&cursor[r], 1);
        ssr[pos] = s;
        return;
    }
    const int tid = threadIdx.x;
    const int wave = tid >> 6, lane = tid & 63;
    const int quad = lane >> 4, l15 = lane & 15;
    const int nbase = blockIdx.x * 64 + wave * 16;

    int n = nbase + l15;
    int nrow = n < NN ? n : NN - 1;

    bf16x8 ah[4];
    #pragma unroll
    for (int ks = 0; ks < 4; ks++)
        ah[ks] = load_frag_f32(h + (size_t)nrow * DD + ks * 32 + quad * 8);

    f32x4 acca[8], accb[8];
    #pragma unroll
    for (int nt = 0; nt < 8; nt++) {
        acca[nt] = f32x4{0.f, 0.f, 0.f, 0.f};
        accb[nt] = f32x4{0.f, 0.f, 0.f, 0.f};
    }

    #pragma unroll
    for (int ks = 0; ks < 4; ks++) {
        #pragma unroll
        for (int nt = 0; nt < 8; nt++)
            acca[nt] = __builtin_amdgcn_mfma_f32_16x16x32_bf16(
                ah[ks], w1a_pack[(nt * 4 + ks) * 64 + lane], acca[nt], 0, 0, 0);
        #pragma unroll
        for (int nt = 0; nt < 8; nt++)
            accb[nt] = __builtin_amdgcn_mfma_f32_16x16x32_bf16(
                ah[ks], w1b_pack[(nt * 4 + ks) * 64 + lane], accb[nt], 0, 0, 0);
    }

    #pragma unroll
    for (int nt = 0; nt < 8; nt++) {
        int d = nt * 16 + l15;
        float b1v = b1[d];
        #pragma unroll
        for (int r = 0; r < 4; r++) {
            int n2 = nbase + quad * 4 + r;
            if (n2 < NN) {
                G[(size_t)n2 * 256 + d]       = (unsigned short)f2bf(acca[nt][r] + b1v);
                G[(size_t)n2 * 256 + 128 + d] = (unsigned short)f2bf(accb[nt][r]);
            }
        }
    }
}

// ---- edge kernel v11: PADDED-TILE, sentinel-free, lb4 (budget = VGPR+AGPR <= 128).
//      Full tiles take a uniform fast path (no masks/clamps). Single-tile buckets
//      plain-store; multi-tile buckets atomicAdd onto alloc-zeroed rows. ----
__global__ __launch_bounds__(256, 4) void edge_kernel(
    const unsigned short* __restrict__ G,      // [NN][256] bf16: [G1a+b1 | G1b]
    const float* __restrict__ coords,          // [NN][3] (L2-resident, 600 KB)
    const int* __restrict__ ssr,               // [padded slots] sender (garbage in pads)
    const int2* __restrict__ tinfo,            // [tiles] (receiver|flag, bucket_end)
    const int* __restrict__ tileCtr,           // [1] total tile count
    const bf16x8* __restrict__ w2_pack,        // 32 KB
    const float* __restrict__ w1c,             // [128] fp32, k-order
    const float* __restrict__ b2,
    float* __restrict__ agg)                   // [NN][128] fp32
{
    __shared__ float w1c_s[4][128];

    const int tid = threadIdx.x;
    const int wave = tid >> 6, lane = tid & 63;
    const int quad = lane >> 4, l15 = lane & 15;

    w1c_s[wave][lane] = w1c[lane];
    w1c_s[wave][64 + lane] = w1c[64 + lane];
    asm volatile("s_waitcnt lgkmcnt(0)" ::: "memory");   // wave-local LDS only

    float b2f[8];
    #pragma unroll
    for (int nt = 0; nt < 8; nt++) b2f[nt] = b2[nt * 16 + l15];

    const int ntot = *tileCtr;                 // total real tiles
    const int tbase = (blockIdx.x * 4 + wave) * 4;

    #pragma unroll
    for (int mt = 0; mt < 4; mt++) {
        const int t = tbase + mt;
        if (t >= ntot) continue;               // tail slots: nothing allocated

        const int2 ti = tinfo[t];              // uniform across wave
        const bool single = ti.x < 0;          // sole-writer bucket -> plain store
        const int rnode = ti.x & 0x7FFFFFFF;
        const int end = ti.y;                  // first invalid slot
        const int slot0 = t * 16;
        const bool fullt = (slot0 + 16 <= end);    // uniform: tile has 16 real edges

        // receiver-side row (uniform; L1/L2-hot since adjacent tiles share it)
        bf16x8 gb[4];
        #pragma unroll
        for (int ks = 0; ks < 4; ks++)
            gb[ks] = *(const bf16x8*)(G + (size_t)rnode * 256 + 128 + ks * 32 + quad * 8);
        float rx = coords[3 * rnode + 0];
        float ry = coords[3 * rnode + 1];
        float rz = coords[3 * rnode + 2];

        // this tile's 16 slots (replicated across quads); positional validity
        int sraw = ssr[slot0 + l15];                     // garbage in pad slots
        int sc = fullt ? sraw
                       : ((slot0 + l15 < end) ? sraw : rnode);

        bf16x8 ga[4];
        #pragma unroll
        for (int ks = 0; ks < 4; ks++)
            ga[ks] = *(const bf16x8*)(G + (size_t)sc * 256 + ks * 32 + quad * 8);
        float dx = coords[3 * sc + 0] - rx;
        float dy = coords[3 * sc + 1] - ry;
        float dz = coords[3 * sc + 2] - rz;
        float dist = sqrtf(dx * dx + dy * dy + dz * dz);

        // layer-1 epilogue in A-frag layout (w1c from LDS, quad-broadcast)
        bf16x8 m1f[4];
        #pragma unroll
        for (int ks = 0; ks < 4; ks++) {
            f32x4 c0 = *(const f32x4*)&w1c_s[wave][ks * 32 + quad * 8];
            f32x4 c1 = *(const f32x4*)&w1c_s[wave][ks * 32 + quad * 8 + 4];
            #pragma unroll
            for (int j = 0; j < 4; j++) {
                float pre0 = bf2f(ga[ks][j])     + bf2f(gb[ks][j])     + dist * c0[j];
                float pre1 = bf2f(ga[ks][4 + j]) + bf2f(gb[ks][4 + j]) + dist * c1[j];
                m1f[ks][j]     = f2bf(fast_silu(pre0));
                m1f[ks][4 + j] = f2bf(fast_silu(pre1));
            }
        }

        // layer 2: W2 MFMA
        f32x4 sv[8];
        #pragma unroll
        for (int nt = 0; nt < 8; nt++) sv[nt] = f32x4{0.f, 0.f, 0.f, 0.f};
        #pragma unroll
        for (int ks = 0; ks < 4; ks++)
            #pragma unroll
            for (int nt = 0; nt < 8; nt++)
                sv[nt] = __builtin_amdgcn_mfma_f32_16x16x32_bf16(
                    m1f[ks], w2_pack[(nt * 4 + ks) * 64 + lane], sv[nt], 0, 0, 0);

        // silu + row accumulate (C row = quad*4+r); full tiles skip masking
        float acc[8];
        #pragma unroll
        for (int nt = 0; nt < 8; nt++) acc[nt] = 0.f;
        if (fullt) {
            #pragma unroll
            for (int nt = 0; nt < 8; nt++)
                #pragma unroll
                for (int r = 0; r < 4; r++)
                    acc[nt] += fast_silu(sv[nt][r] + b2f[nt]);
        } else {
            float mk[4];
            #pragma unroll
            for (int r = 0; r < 4; r++)
                mk[r] = (slot0 + quad * 4 + r < end) ? 1.f : 0.f;
            #pragma unroll
            for (int nt = 0; nt < 8; nt++)
                #pragma unroll
                for (int r = 0; r < 4; r++) {
                    float v = fast_silu(sv[nt][r] + b2f[nt]);
                    acc[nt] = fmaf(v, mk[r], acc[nt]);
                }
        }

        // cross-quad reduce; one full-row flush per tile (store or atomic)
        #pragma unroll
        for (int nt = 0; nt < 8; nt++) {
            float s = acc[nt];
            s += __shfl_xor(s, 16);
            s += __shfl_xor(s, 32);
            acc[nt] = s;
        }
        size_t base = (size_t)rnode * DD + l15;
        if (single) {                          // sole writer: plain coalesced store
            agg[base + (quad * 2 + 0) * 16] = acc[quad * 2 + 0];
            agg[base + (quad * 2 + 1) * 16] = acc[quad * 2 + 1];
        } else {                               // multi-tile: add onto zeroed row
            unsafeAtomicAdd(&agg[base + (quad * 2 + 0) * 16], acc[quad * 2 + 0]);
            unsafeAtomicAdd(&agg[base + (quad * 2 + 1) * 16], acc[quad * 2 + 1]);
        }
    }
}

// ---- node kernel: out = h + U2*silu(U1a*h + U1b*agg + c1) + c2
//      (A-frags converted from fp32 hf at use; rows are L1/L2-hot from the
//       residual read of the same 64-row block) ----
__global__ __launch_bounds__(256, 4) void node_kernel(
    const float* __restrict__ hf,
    const float* __restrict__ agg,
    const bf16x8* __restrict__ u1a_pack,
    const bf16x8* __restrict__ u1b_pack,
    const bf16x8* __restrict__ u2_pack,
    const float* __restrict__ c1,
    const float* __restrict__ c2,
    float* __restrict__ out)
{
    __shared__ unsigned short u1s[4][16][136];

    const int tid = threadIdx.x;
    const int wave = tid >> 6, lane = tid & 63;
    const int quad = lane >> 4, l15 = lane & 15;
    const int nbase = blockIdx.x * 64 + wave * 16;

    int n = nbase + l15;
    int nrow = n < NN ? n : NN - 1;

    float c1v[8];
    #pragma unroll
    for (int nt = 0; nt < 8; nt++) c1v[nt] = c1[nt * 16 + l15];

    bf16x8 ah[4], ag[4];
    #pragma unroll
    for (int ks = 0; ks < 4; ks++) {
        ah[ks] = load_frag_f32(hf + (size_t)nrow * DD + ks * 32 + quad * 8);
        ag[ks] = load_frag_f32(agg + (size_t)nrow * DD + ks * 32 + quad * 8);
    }

    f32x4 acc[8];
    #pragma unroll
    for (int nt = 0; nt < 8; nt++) acc[nt] = f32x4{0.f, 0.f, 0.f, 0.f};

    #pragma unroll
    for (int ks = 0; ks < 4; ks++) {
        #pragma unroll
        for (int nt = 0; nt < 8; nt++)
            acc[nt] = __builtin_amdgcn_mfma_f32_16x16x32_bf16(
                ah[ks], u1a_pack[(nt * 4 + ks) * 64 + lane], acc[nt], 0, 0, 0);
        #pragma unroll
        for (int nt = 0; nt < 8; nt++)
            acc[nt] = __builtin_amdgcn_mfma_f32_16x16x32_bf16(
                ag[ks], u1b_pack[(nt * 4 + ks) * 64 + lane], acc[nt], 0, 0, 0);
    }

    #pragma unroll
    for (int nt = 0; nt < 8; nt++) {
        int d = nt * 16 + l15;
        #pragma unroll
        for (int r = 0; r < 4; r++) {
            float pre = acc[nt][r] + c1v[nt];
            u1s[wave][quad * 4 + r][d] = (unsigned short)f2bf(fast_silu(pre));
        }
    }
    asm volatile("s_waitcnt lgkmcnt(0)" ::: "memory");

    bf16x8 a2[4];
    #pragma unroll
    for (int ks = 0; ks < 4; ks++)
        a2[ks] = *(const bf16x8*)(&u1s[wave][l15][ks * 32 + quad * 8]);

    f32x4 acc2[8];
    #pragma unroll
    for (int nt = 0; nt < 8; nt++) acc2[nt] = f32x4{0.f, 0.f, 0.f, 0.f};

    #pragma unroll
    for (int ks = 0; ks < 4; ks++)
        #pragma unroll
        for (int nt = 0; nt < 8; nt++)
            acc2[nt] = __builtin_amdgcn_mfma_f32_16x16x32_bf16(
                a2[ks], u2_pack[(nt * 4 + ks) * 64 + lane], acc2[nt], 0, 0, 0);

    #pragma unroll
    for (int nt = 0; nt < 8; nt++) {
        int d = nt * 16 + l15;
        float c2v = c2[d];
        #pragma unroll
        for (int r = 0; r < 4; r++) {
            int n2 = nbase + quad * 4 + r;
            if (n2 < NN) {
                size_t idx = (size_t)n2 * DD + d;
                out[idx] = hf[idx] + acc2[nt][r] + c2v;
            }
        }
    }
}

extern "C" void kernel_launch(void* const* d_in, const int* in_sizes, int n_in,
                              void* d_out, int out_size, void* d_ws, size_t ws_size,
                              hipStream_t stream) {
    const float* h      = (const float*)d_in[0];
    const float* coords = (const float*)d_in[1];
    const int* ei       = (const int*)d_in[2];   // int64 in reference -> int32 from harness
    const float* W1 = (const float*)d_in[3];
    const float* b1 = (const float*)d_in[4];
    const float* W2 = (const float*)d_in[5];
    const float* b2 = (const float*)d_in[6];
    const float* U1 = (const float*)d_in[7];
    const float* c1 = (const float*)d_in[8];
    const float* U2 = (const float*)d_in[9];
    const float* c2 = (const float*)d_in[10];
    float* out = (float*)d_out;

    char* ws = (char*)d_ws;
    float* agg            = (float*)ws;                          // 25,600,000 B fp32 [NN][128]
    unsigned short* packs = (unsigned short*)(ws + 38400000);    //    196,608 B packed weights
    float* w1c            = (float*)(ws + 38600000);             //        512 B
    unsigned short* G     = (unsigned short*)(ws + 38700000);    // 25,600,000 B bf16 [NN][256]
    int* cnt              = (int*)(ws + 64300000);               //    200,000 B
    int* tileCtr          = (int*)(ws + 64500000);               //          4 B (memset with cnt)
    int* cursor           = (int*)(ws + 64500008);               //    200,000 B scatter cursor
    int2* tinfo           = (int2*)(ws + 64700008);              //    800,000 B (recv|flag, end)
    int* ssr              = (int*)(ws + 65500008);               //  6,400,000 B padded senders
    const bf16x8* w1a = (const bf16x8*)(packs);
    const bf16x8* w1b = (const bf16x8*)(packs + 16384);
    const bf16x8* w2p = (const bf16x8*)(packs + 32768);
    const bf16x8* u1a = (const bf16x8*)(packs + 49152);
    const bf16x8* u1b = (const bf16x8*)(packs + 65536);
    const bf16x8* u2p = (const bf16x8*)(packs + 81920);

    hipMemsetAsync(cnt, 0, 200004, stream);                      // cnt + tileCtr
    prep_all_kernel<<<3510, 256, 0, stream>>>(ei, cnt, W1, W2, U1, U2, packs, w1c);
    alloc_kernel<<<196, 256, 0, stream>>>(cnt, tileCtr, cursor, tinfo, (float4*)agg);
    prep_g_scatter_kernel<<<3907, 256, 0, stream>>>(h, w1a, w1b, b1, G, ei,
                                                    cursor, ssr);
    // edge: 6250 blocks * 4 waves * 4 tiles = 100000 tile slots (>= actual tiles)
    edge_kernel<<<6250, 256, 0, stream>>>(G, coords, ssr, tinfo, tileCtr,
                                          w2p, w1c, b2, agg);
    node_kernel<<<(NN + 63) / 64, 256, 0, stream>>>(h, agg, u1a, u1b, u2p, c1, c2, out);
}

// Round 13
// 379.057 us; speedup vs baseline: 1.0301x; 1.0301x over previous
//
#include <hip/hip_runtime.h>
#include <hip/hip_bf16.h>

#define NN 50000
#define EE 800000
#define DD 128

typedef __attribute__((ext_vector_type(8))) short bf16x8;
typedef __attribute__((ext_vector_type(4))) float f32x4;

__device__ __forceinline__ short f2bf(float f) {
    __hip_bfloat16 h = __float2bfloat16(f);
    return __builtin_bit_cast(short, h);
}

__device__ __forceinline__ float bf2f(short s) {
    unsigned int u = ((unsigned int)(unsigned short)s) << 16;
    return __builtin_bit_cast(float, u);
}

// fast silu: v_rcp_f32 instead of the ~10-instr exact-div sequence.
__device__ __forceinline__ float fast_silu(float x) {
    return x * __builtin_amdgcn_rcpf(1.0f + __expf(-x));
}

// convert 8 consecutive floats to a bf16x8 A-fragment
__device__ __forceinline__ bf16x8 load_frag_f32(const float* p) {
    f32x4 a = *(const f32x4*)p;
    f32x4 b = *(const f32x4*)(p + 4);
    bf16x8 t;
    t[0] = f2bf(a[0]); t[1] = f2bf(a[1]); t[2] = f2bf(a[2]); t[3] = f2bf(a[3]);
    t[4] = f2bf(b[0]); t[5] = f2bf(b[1]); t[6] = f2bf(b[2]); t[7] = f2bf(b[3]);
    return t;
}

// ---- prep_all: blocks [0,3125): receiver histogram.
//      blocks [3125,3510): pack 6 weight blocks into MFMA B-frag order + w1c. ----
__global__ void prep_all_kernel(const int* __restrict__ ei, int* __restrict__ cnt,
                                const float* __restrict__ W1, const float* __restrict__ W2,
                                const float* __restrict__ U1, const float* __restrict__ U2,
                                unsigned short* __restrict__ packs,
                                float* __restrict__ w1c_out) {
    if (blockIdx.x < 3125) {
        int e = blockIdx.x * 256 + threadIdx.x;          // 800000 exactly
        atomicAdd(&cnt[ei[EE + e]], 1);                  // receiver histogram
        return;
    }
    int t = (blockIdx.x - 3125) * blockDim.x + threadIdx.x;
    if (t >= 98304) {
        if (t < 98432) { int d = t - 98304; w1c_out[d] = W1[d * 257 + 256]; }
        return;
    }
    int mat = t >> 14;
    int r = t & 16383;
    int j = r & 7;
    int lane = (r >> 3) & 63;
    int f = r >> 9;            // 0..31
    int ks = f & 3, nt = f >> 2;
    int n = nt * 16 + (lane & 15);
    int k = ks * 32 + (lane >> 4) * 8 + j;
    float v;
    switch (mat) {
        case 0: v = W1[n * 257 + k];        break;  // W1a (vs h_sender)
        case 1: v = W1[n * 257 + 128 + k];  break;  // W1b (vs h_receiver)
        case 2: v = W2[n * 128 + k];        break;  // W2
        case 3: v = U1[n * 256 + k];        break;  // U1a (vs h)
        case 4: v = U1[n * 256 + 128 + k];  break;  // U1b (vs agg)
        default: v = U2[n * 128 + k];       break;  // U2
    }
    packs[t] = (unsigned short)f2bf(v);
}

// ---- alloc: TAIL-PACKED allocation. Receiver i gets floor(c/16) full tiles
//      (tinfoA) and its c%16 tail edges go densely into the shared tail pool.
//      Total tiles <= 50001 (vs ~76.5K padded). agg is memset-zeroed; all
//      edge flushes are atomicAdd -> no writer-count tracking needed. ----
__global__ void alloc_kernel(const int* __restrict__ cnt, int* __restrict__ ctrs,
                             int* __restrict__ fullbase, int* __restrict__ tailbase,
                             int* __restrict__ tinfoA) {
    int i = blockIdx.x * 256 + threadIdx.x;              // 196 blocks: 50176 >= NN
    if (i >= NN) return;
    int c = cnt[i];
    int nf = c >> 4, tc = c & 15;
    if (nf) {
        int tb = atomicAdd(&ctrs[0], nf);
        fullbase[i] = tb << 4;
        for (int k = 0; k < nf; k++) tinfoA[tb + k] = i;
    }
    if (tc) tailbase[i] = atomicAdd(&ctrs[1], tc);
}

// ---- prep_g (blocks [0,782)) + scatter (blocks [782,3907)) ----
__global__ __launch_bounds__(256, 2) void prep_g_scatter_kernel(
    const float* __restrict__ h,
    const bf16x8* __restrict__ w1a_pack,
    const bf16x8* __restrict__ w1b_pack,
    const float* __restrict__ b1,
    unsigned short* __restrict__ G,
    const int* __restrict__ ei,
    const int* __restrict__ cnt,
    int* __restrict__ cursor,
    const int* __restrict__ fullbase,
    const int* __restrict__ tailbase,
    int* __restrict__ ssrA,
    int2* __restrict__ pool)
{
    if (blockIdx.x >= 782) {
        // route each edge to its receiver's full region or tail region
        int e = (blockIdx.x - 782) * 256 + threadIdx.x;   // 3125*256 = 800000 exactly
        int s = ei[e], r = ei[EE + e];
        int p = atomicAdd(&cursor[r], 1);                 // 0-based within receiver
        int thr = cnt[r] & ~15;
        if (p < thr) ssrA[fullbase[r] + p] = s;
        else         pool[tailbase[r] + p - thr] = make_int2(s, r);
        return;
    }
    const int tid = threadIdx.x;
    const int wave = tid >> 6, lane = tid & 63;
    const int quad = lane >> 4, l15 = lane & 15;
    const int nbase = blockIdx.x * 64 + wave * 16;

    int n = nbase + l15;
    int nrow = n < NN ? n : NN - 1;

    bf16x8 ah[4];
    #pragma unroll
    for (int ks = 0; ks < 4; ks++)
        ah[ks] = load_frag_f32(h + (size_t)nrow * DD + ks * 32 + quad * 8);

    f32x4 acca[8], accb[8];
    #pragma unroll
    for (int nt = 0; nt < 8; nt++) {
        acca[nt] = f32x4{0.f, 0.f, 0.f, 0.f};
        accb[nt] = f32x4{0.f, 0.f, 0.f, 0.f};
    }

    #pragma unroll
    for (int ks = 0; ks < 4; ks++) {
        #pragma unroll
        for (int nt = 0; nt < 8; nt++)
            acca[nt] = __builtin_amdgcn_mfma_f32_16x16x32_bf16(
                ah[ks], w1a_pack[(nt * 4 + ks) * 64 + lane], acca[nt], 0, 0, 0);
        #pragma unroll
        for (int nt = 0; nt < 8; nt++)
            accb[nt] = __builtin_amdgcn_mfma_f32_16x16x32_bf16(
                ah[ks], w1b_pack[(nt * 4 + ks) * 64 + lane], accb[nt], 0, 0, 0);
    }

    #pragma unroll
    for (int nt = 0; nt < 8; nt++) {
        int d = nt * 16 + l15;
        float b1v = b1[d];
        #pragma unroll
        for (int r = 0; r < 4; r++) {
            int n2 = nbase + quad * 4 + r;
            if (n2 < NN) {
                G[(size_t)n2 * 256 + d]       = (unsigned short)f2bf(acca[nt][r] + b1v);
                G[(size_t)n2 * 256 + 128 + d] = (unsigned short)f2bf(accb[nt][r]);
            }
        }
    }
}

// ---- edge kernel v12: TAIL-PACKED. Tiles [0, nfullT): one receiver, 16 real
//      edges, uniform fast path. Tiles [nfullT, ntiles): mixed-receiver tail
//      pool, per-row gathers + ballot-segmented reduce (no MFMA in the dynamic
//      segment loop -> spill-safe). All flushes atomicAdd onto memset-zeroed agg. ----
__global__ __launch_bounds__(256, 4) void edge_kernel(
    const unsigned short* __restrict__ G,      // [NN][256] bf16: [G1a+b1 | G1b]
    const float* __restrict__ coords,          // [NN][3] (L2-resident, 600 KB)
    const int* __restrict__ ssrA,              // full-tile senders
    const int2* __restrict__ pool,             // tail slots (sender, receiver)
    const int* __restrict__ tinfoA,            // [full tiles] receiver
    const int* __restrict__ ctrs,              // [0]=full tiles, [1]=tail slots
    const bf16x8* __restrict__ w2_pack,        // 32 KB
    const float* __restrict__ w1c,             // [128] fp32, k-order
    const float* __restrict__ b2,
    float* __restrict__ agg)                   // [NN][128] fp32, pre-zeroed
{
    __shared__ float w1c_s[4][128];

    const int tid = threadIdx.x;
    const int wave = tid >> 6, lane = tid & 63;
    const int quad = lane >> 4, l15 = lane & 15;

    w1c_s[wave][lane] = w1c[lane];
    w1c_s[wave][64 + lane] = w1c[64 + lane];
    asm volatile("s_waitcnt lgkmcnt(0)" ::: "memory");   // wave-local LDS only

    float b2f[8];
    #pragma unroll
    for (int nt = 0; nt < 8; nt++) b2f[nt] = b2[nt * 16 + l15];

    const int nfullT = ctrs[0];
    const int ntail  = ctrs[1];
    const int ntiles = nfullT + ((ntail + 15) >> 4);
    const int tbase = (blockIdx.x * 4 + wave) * 4;

    #pragma unroll
    for (int mt = 0; mt < 4; mt++) {
        const int t = tbase + mt;
        if (t >= ntiles) continue;

        const bool full = t < nfullT;          // uniform across wave
        bf16x8 ga[4], gb[4];
        float dist;
        int rnode = 0;                         // full-path receiver
        int rr = 0;                            // tail-path per-row receiver

        if (full) {
            rnode = tinfoA[t];
            #pragma unroll
            for (int ks = 0; ks < 4; ks++)
                gb[ks] = *(const bf16x8*)(G + (size_t)rnode * 256 + 128 + ks * 32 + quad * 8);
            float rx = coords[3 * rnode + 0];
            float ry = coords[3 * rnode + 1];
            float rz = coords[3 * rnode + 2];
            int sc = ssrA[t * 16 + l15];       // all 16 slots real
            #pragma unroll
            for (int ks = 0; ks < 4; ks++)
                ga[ks] = *(const bf16x8*)(G + (size_t)sc * 256 + ks * 32 + quad * 8);
            float dx = coords[3 * sc + 0] - rx;
            float dy = coords[3 * sc + 1] - ry;
            float dz = coords[3 * sc + 2] - rz;
            dist = sqrtf(dx * dx + dy * dy + dz * dz);
        } else {
            const int pbase = (t - nfullT) * 16;
            int slot = pbase + l15;
            int cl = slot < ntail ? slot : ntail - 1;    // clamp pads to last real
            int2 sd = pool[cl];
            int sc = sd.x; rr = sd.y;
            #pragma unroll
            for (int ks = 0; ks < 4; ks++) {
                ga[ks] = *(const bf16x8*)(G + (size_t)sc * 256 + ks * 32 + quad * 8);
                gb[ks] = *(const bf16x8*)(G + (size_t)rr * 256 + 128 + ks * 32 + quad * 8);
            }
            float dx = coords[3 * sc + 0] - coords[3 * rr + 0];
            float dy = coords[3 * sc + 1] - coords[3 * rr + 1];
            float dz = coords[3 * sc + 2] - coords[3 * rr + 2];
            dist = sqrtf(dx * dx + dy * dy + dz * dz);
        }

        // layer-1 epilogue in A-frag layout (w1c from LDS, quad-broadcast)
        bf16x8 m1f[4];
        #pragma unroll
        for (int ks = 0; ks < 4; ks++) {
            f32x4 c0 = *(const f32x4*)&w1c_s[wave][ks * 32 + quad * 8];
            f32x4 c1 = *(const f32x4*)&w1c_s[wave][ks * 32 + quad * 8 + 4];
            #pragma unroll
            for (int j = 0; j < 4; j++) {
                float pre0 = bf2f(ga[ks][j])     + bf2f(gb[ks][j])     + dist * c0[j];
                float pre1 = bf2f(ga[ks][4 + j]) + bf2f(gb[ks][4 + j]) + dist * c1[j];
                m1f[ks][j]     = f2bf(fast_silu(pre0));
                m1f[ks][4 + j] = f2bf(fast_silu(pre1));
            }
        }

        // layer 2: W2 MFMA
        f32x4 sv[8];
        #pragma unroll
        for (int nt = 0; nt < 8; nt++) sv[nt] = f32x4{0.f, 0.f, 0.f, 0.f};
        #pragma unroll
        for (int ks = 0; ks < 4; ks++)
            #pragma unroll
            for (int nt = 0; nt < 8; nt++)
                sv[nt] = __builtin_amdgcn_mfma_f32_16x16x32_bf16(
                    m1f[ks], w2_pack[(nt * 4 + ks) * 64 + lane], sv[nt], 0, 0, 0);

        if (full) {
            // no masks: all 16 rows real, one receiver
            float acc[8];
            #pragma unroll
            for (int nt = 0; nt < 8; nt++) {
                float s = 0.f;
                #pragma unroll
                for (int r = 0; r < 4; r++)
                    s += fast_silu(sv[nt][r] + b2f[nt]);
                s += __shfl_xor(s, 16);
                s += __shfl_xor(s, 32);
                acc[nt] = s;
            }
            size_t base = (size_t)rnode * DD + l15;
            unsafeAtomicAdd(&agg[base + (quad * 2 + 0) * 16], acc[quad * 2 + 0]);
            unsafeAtomicAdd(&agg[base + (quad * 2 + 1) * 16], acc[quad * 2 + 1]);
        } else {
            const int pbase = (t - nfullT) * 16;
            // silu + validity mask in place (row = quad*4+r)
            #pragma unroll
            for (int nt = 0; nt < 8; nt++)
                #pragma unroll
                for (int r = 0; r < 4; r++) {
                    float v = fast_silu(sv[nt][r] + b2f[nt]);
                    sv[nt][r] = (pbase + quad * 4 + r < ntail) ? v : 0.f;
                }
            // segment boundaries among rows 0..15 (receiver runs are contiguous)
            int nxt = __shfl(rr, (l15 + 1) & 15);
            unsigned long long bal = __ballot(l15 == 15 || rr != nxt);
            unsigned m = (unsigned)(bal & 0xFFFFull);
            int i0 = 0;
            while (m) {                        // ~2 segments avg; no MFMA inside
                int b = (int)__builtin_ctz(m);
                m &= m - 1;
                float tot[8];
                #pragma unroll
                for (int nt = 0; nt < 8; nt++) {
                    float s = 0.f;
                    #pragma unroll
                    for (int r = 0; r < 4; r++) {
                        int row = quad * 4 + r;
                        s += (row >= i0 && row <= b) ? sv[nt][r] : 0.f;
                    }
                    s += __shfl_xor(s, 16);
                    s += __shfl_xor(s, 32);
                    tot[nt] = s;
                }
                int rcv = __shfl(rr, i0);      // uniform receiver of this run
                size_t base = (size_t)rcv * DD + l15;
                unsafeAtomicAdd(&agg[base + (quad * 2 + 0) * 16], tot[quad * 2 + 0]);
                unsafeAtomicAdd(&agg[base + (quad * 2 + 1) * 16], tot[quad * 2 + 1]);
                i0 = b + 1;
            }
        }
    }
}

// ---- node kernel: out = h + U2*silu(U1a*h + U1b*agg + c1) + c2 ----
__global__ __launch_bounds__(256, 4) void node_kernel(
    const float* __restrict__ hf,
    const float* __restrict__ agg,
    const bf16x8* __restrict__ u1a_pack,
    const bf16x8* __restrict__ u1b_pack,
    const bf16x8* __restrict__ u2_pack,
    const float* __restrict__ c1,
    const float* __restrict__ c2,
    float* __restrict__ out)
{
    __shared__ unsigned short u1s[4][16][136];

    const int tid = threadIdx.x;
    const int wave = tid >> 6, lane = tid & 63;
    const int quad = lane >> 4, l15 = lane & 15;
    const int nbase = blockIdx.x * 64 + wave * 16;

    int n = nbase + l15;
    int nrow = n < NN ? n : NN - 1;

    float c1v[8];
    #pragma unroll
    for (int nt = 0; nt < 8; nt++) c1v[nt] = c1[nt * 16 + l15];

    bf16x8 ah[4], ag[4];
    #pragma unroll
    for (int ks = 0; ks < 4; ks++) {
        ah[ks] = load_frag_f32(hf + (size_t)nrow * DD + ks * 32 + quad * 8);
        ag[ks] = load_frag_f32(agg + (size_t)nrow * DD + ks * 32 + quad * 8);
    }

    f32x4 acc[8];
    #pragma unroll
    for (int nt = 0; nt < 8; nt++) acc[nt] = f32x4{0.f, 0.f, 0.f, 0.f};

    #pragma unroll
    for (int ks = 0; ks < 4; ks++) {
        #pragma unroll
        for (int nt = 0; nt < 8; nt++)
            acc[nt] = __builtin_amdgcn_mfma_f32_16x16x32_bf16(
                ah[ks], u1a_pack[(nt * 4 + ks) * 64 + lane], acc[nt], 0, 0, 0);
        #pragma unroll
        for (int nt = 0; nt < 8; nt++)
            acc[nt] = __builtin_amdgcn_mfma_f32_16x16x32_bf16(
                ag[ks], u1b_pack[(nt * 4 + ks) * 64 + lane], acc[nt], 0, 0, 0);
    }

    #pragma unroll
    for (int nt = 0; nt < 8; nt++) {
        int d = nt * 16 + l15;
        #pragma unroll
        for (int r = 0; r < 4; r++) {
            float pre = acc[nt][r] + c1v[nt];
            u1s[wave][quad * 4 + r][d] = (unsigned short)f2bf(fast_silu(pre));
        }
    }
    asm volatile("s_waitcnt lgkmcnt(0)" ::: "memory");

    bf16x8 a2[4];
    #pragma unroll
    for (int ks = 0; ks < 4; ks++)
        a2[ks] = *(const bf16x8*)(&u1s[wave][l15][ks * 32 + quad * 8]);

    f32x4 acc2[8];
    #pragma unroll
    for (int nt = 0; nt < 8; nt++) acc2[nt] = f32x4{0.f, 0.f, 0.f, 0.f};

    #pragma unroll
    for (int ks = 0; ks < 4; ks++)
        #pragma unroll
        for (int nt = 0; nt < 8; nt++)
            acc2[nt] = __builtin_amdgcn_mfma_f32_16x16x32_bf16(
                a2[ks], u2_pack[(nt * 4 + ks) * 64 + lane], acc2[nt], 0, 0, 0);

    #pragma unroll
    for (int nt = 0; nt < 8; nt++) {
        int d = nt * 16 + l15;
        float c2v = c2[d];
        #pragma unroll
        for (int r = 0; r < 4; r++) {
            int n2 = nbase + quad * 4 + r;
            if (n2 < NN) {
                size_t idx = (size_t)n2 * DD + d;
                out[idx] = hf[idx] + acc2[nt][r] + c2v;
            }
        }
    }
}

extern "C" void kernel_launch(void* const* d_in, const int* in_sizes, int n_in,
                              void* d_out, int out_size, void* d_ws, size_t ws_size,
                              hipStream_t stream) {
    const float* h      = (const float*)d_in[0];
    const float* coords = (const float*)d_in[1];
    const int* ei       = (const int*)d_in[2];   // int64 in reference -> int32 from harness
    const float* W1 = (const float*)d_in[3];
    const float* b1 = (const float*)d_in[4];
    const float* W2 = (const float*)d_in[5];
    const float* b2 = (const float*)d_in[6];
    const float* U1 = (const float*)d_in[7];
    const float* c1 = (const float*)d_in[8];
    const float* U2 = (const float*)d_in[9];
    const float* c2 = (const float*)d_in[10];
    float* out = (float*)d_out;

    char* ws = (char*)d_ws;
    float* agg            = (float*)ws;                          // 25,600,000 B fp32 [NN][128]
    unsigned short* packs = (unsigned short*)(ws + 38400000);    //    196,608 B packed weights
    float* w1c            = (float*)(ws + 38600000);             //        512 B
    unsigned short* G     = (unsigned short*)(ws + 38700000);    // 25,600,000 B bf16 [NN][256]
    int* cnt              = (int*)(ws + 64300000);               //    200,000 B
    int* cursor           = (int*)(ws + 64500000);               //    200,000 B (0-based)
    int* ctrs             = (int*)(ws + 64700000);               //          8 B [full tiles, tail slots]
    int* fullbase         = (int*)(ws + 64700008);               //    200,000 B
    int* tailbase         = (int*)(ws + 64900008);               //    200,000 B
    int* tinfoA           = (int*)(ws + 65100008);               //    200,000 B full-tile receivers
    int* ssrA             = (int*)(ws + 65300008);               //  3,200,000 B full-tile senders
    int2* pool            = (int2*)(ws + 68500008);              //  4,000,000 B tail (send, recv)
    const bf16x8* w1a = (const bf16x8*)(packs);
    const bf16x8* w1b = (const bf16x8*)(packs + 16384);
    const bf16x8* w2p = (const bf16x8*)(packs + 32768);
    const bf16x8* u1a = (const bf16x8*)(packs + 49152);
    const bf16x8* u1b = (const bf16x8*)(packs + 65536);
    const bf16x8* u2p = (const bf16x8*)(packs + 81920);

    hipMemsetAsync(agg, 0, 25600000, stream);                    // all flushes are +=
    hipMemsetAsync(cnt, 0, 400008, stream);                      // cnt + cursor + ctrs
    prep_all_kernel<<<3510, 256, 0, stream>>>(ei, cnt, W1, W2, U1, U2, packs, w1c);
    alloc_kernel<<<196, 256, 0, stream>>>(cnt, ctrs, fullbase, tailbase, tinfoA);
    prep_g_scatter_kernel<<<3907, 256, 0, stream>>>(h, w1a, w1b, b1, G, ei, cnt,
                                                    cursor, fullbase, tailbase,
                                                    ssrA, pool);
    // edge: 3126 blocks * 16 tile-slots = 50016 >= 50001 max packed tiles
    edge_kernel<<<3126, 256, 0, stream>>>(G, coords, ssrA, pool, tinfoA, ctrs,
                                          w2p, w1c, b2, agg);
    node_kernel<<<(NN + 63) / 64, 256, 0, stream>>>(h, agg, u1a, u1b, u2p, c1, c2, out);
}